// Round 1
// baseline (5223.819 us; speedup 1.0000x reference)
//
#include <hip/hip_runtime.h>
#include <math.h>

#define N_TOT 16384
#define C_TOT 1000
#define D_TOT 512

#define BN 128
#define BC 64
#define BD 16
#define FS 132   // fT leading-dim stride (128 rows + 4 pad)
#define CS 68    // cT leading-dim stride (64 rows + 4 pad)

#define EPS_F 1e-8f
#define SCALE_F 0.04419417382415922f  // 1/sqrt(512)

// ---------------- fsq / csq precompute: one wave per row ----------------
__global__ __launch_bounds__(256)
void sq_kernel(const float* __restrict__ F, const float* __restrict__ Cc,
               float* __restrict__ sqout) {
    int gw   = (blockIdx.x * 256 + threadIdx.x) >> 6;   // global wave id = row
    int lane = threadIdx.x & 63;
    if (gw >= N_TOT + C_TOT) return;
    const float* src = (gw < N_TOT) ? (F + (size_t)gw * D_TOT)
                                    : (Cc + (size_t)(gw - N_TOT) * D_TOT);
    float4 a = *(const float4*)(src + lane * 4);
    float4 b = *(const float4*)(src + 256 + lane * 4);
    float acc = a.x * a.x;
    acc = fmaf(a.y, a.y, acc);
    acc = fmaf(a.z, a.z, acc);
    acc = fmaf(a.w, a.w, acc);
    acc = fmaf(b.x, b.x, acc);
    acc = fmaf(b.y, b.y, acc);
    acc = fmaf(b.z, b.z, acc);
    acc = fmaf(b.w, b.w, acc);
    #pragma unroll
    for (int off = 32; off > 0; off >>= 1)
        acc += __shfl_xor(acc, off);
    if (lane == 0) sqout[gw] = acc;
}

// ---------------- fused L1 / sq-sum main kernel ----------------
__global__ __launch_bounds__(256, 3)
void dist_main(const float* __restrict__ F, const float* __restrict__ Cc,
               const float* __restrict__ sqbuf, float* __restrict__ out) {
    __shared__ float fT[BD][FS];
    __shared__ float cT[BD][CS];

    const int tid = threadIdx.x;
    const int tx  = tid & 15;   // centroid direction, 4 cols each
    const int ty  = tid >> 4;   // feature direction, 8 rows each
    const int c0  = blockIdx.x * BC;
    const int n0  = blockIdx.y * BN;

    // staging coords: thread loads float4 at depth sdq for row srow (and srow+64 for f)
    const int srow = tid >> 2;          // 0..63
    const int sdq  = (tid & 3) << 2;    // 0,4,8,12

    const float* fptr0 = F + (size_t)(n0 + srow) * D_TOT + sdq;
    const float* fptr1 = fptr0 + (size_t)64 * D_TOT;
    const int    ccol  = c0 + srow;
    const float* cptr  = Cc + (size_t)ccol * D_TOT + sdq;
    const bool   cok   = (ccol < C_TOT);

    float l1[8][4];
    float sq[8][4];
    #pragma unroll
    for (int i = 0; i < 8; ++i)
        #pragma unroll
        for (int j = 0; j < 4; ++j) { l1[i][j] = 0.f; sq[i][j] = 0.f; }

    for (int d0 = 0; d0 < D_TOT; d0 += BD) {
        float4 fa = *(const float4*)(fptr0 + d0);
        float4 fb = *(const float4*)(fptr1 + d0);
        float4 cv = cok ? *(const float4*)(cptr + d0)
                        : make_float4(0.f, 0.f, 0.f, 0.f);
        __syncthreads();   // previous chunk's reads done
        fT[sdq + 0][srow] = fa.x;
        fT[sdq + 1][srow] = fa.y;
        fT[sdq + 2][srow] = fa.z;
        fT[sdq + 3][srow] = fa.w;
        fT[sdq + 0][srow + 64] = fb.x;
        fT[sdq + 1][srow + 64] = fb.y;
        fT[sdq + 2][srow + 64] = fb.z;
        fT[sdq + 3][srow + 64] = fb.w;
        cT[sdq + 0][srow] = cv.x;
        cT[sdq + 1][srow] = cv.y;
        cT[sdq + 2][srow] = cv.z;
        cT[sdq + 3][srow] = cv.w;
        __syncthreads();

        #pragma unroll
        for (int k = 0; k < BD; ++k) {
            float fr[8], cr[4];
            *(float4*)&fr[0] = *(const float4*)&fT[k][ty * 8];
            *(float4*)&fr[4] = *(const float4*)&fT[k][ty * 8 + 4];
            *(float4*)&cr[0] = *(const float4*)&cT[k][tx * 4];
            #pragma unroll
            for (int i = 0; i < 8; ++i) {
                #pragma unroll
                for (int j = 0; j < 4; ++j) {
                    float d = fr[i] - cr[j];
                    l1[i][j] += fabsf(d);
                    sq[i][j] = fmaf(d, d, sq[i][j]);
                }
            }
        }
    }

    // ---------------- epilogue ----------------
    const float* fsq = sqbuf;
    const float* csq = sqbuf + N_TOT;
    const int n_base = n0 + ty * 8;
    const int c_base = c0 + tx * 4;

    float fs[8], fn[8];
    #pragma unroll
    for (int i = 0; i < 8; ++i) {
        fs[i] = fsq[n_base + i];
        fn[i] = fmaxf(sqrtf(fs[i]), EPS_F);
    }
    float cs[4], cn[4];
    #pragma unroll
    for (int j = 0; j < 4; ++j) {
        int c = c_base + j;
        cs[j] = (c < C_TOT) ? csq[c] : 0.f;
        cn[j] = fmaxf(sqrtf(cs[j]), EPS_F);
    }

    if (c_base < C_TOT) {   // C_TOT % 4 == 0, so a float4 is all-valid or all-invalid
        const size_t NC = (size_t)N_TOT * C_TOT;
        #pragma unroll
        for (int i = 0; i < 8; ++i) {
            float o1[4], o2[4], o3[4];
            #pragma unroll
            for (int j = 0; j < 4; ++j) {
                float s = sq[i][j];
                o1[j] = l1[i][j] * SCALE_F;
                o2[j] = sqrtf(s) * SCALE_F;
                float dot = 0.5f * (fs[i] + cs[j] - s);
                o3[j] = dot * SCALE_F / (fn[i] * cn[j]);
            }
            size_t base = (size_t)(n_base + i) * C_TOT + c_base;
            *(float4*)(out + base)          = make_float4(o1[0], o1[1], o1[2], o1[3]);
            *(float4*)(out + NC + base)     = make_float4(o2[0], o2[1], o2[2], o2[3]);
            *(float4*)(out + 2 * NC + base) = make_float4(o3[0], o3[1], o3[2], o3[3]);
        }
    }
}

extern "C" void kernel_launch(void* const* d_in, const int* in_sizes, int n_in,
                              void* d_out, int out_size, void* d_ws, size_t ws_size,
                              hipStream_t stream) {
    const float* F  = (const float*)d_in[0];
    const float* Cc = (const float*)d_in[1];
    float* out   = (float*)d_out;
    float* sqbuf = (float*)d_ws;   // [N_TOT + C_TOT] floats

    int rows = N_TOT + C_TOT;
    sq_kernel<<<(rows + 3) / 4, 256, 0, stream>>>(F, Cc, sqbuf);
    dist_main<<<dim3(16, 128), 256, 0, stream>>>(F, Cc, sqbuf, out);
}